// Round 1
// baseline (497.727 us; speedup 1.0000x reference)
//
#include <hip/hip_runtime.h>
#include <hip/hip_bf16.h>

// Problem constants (from reference)
#define HID 128
#define NCLS 12
#define NGRAPH 128

// ---------------------------------------------------------------------------
// CSR build: histogram of in-degree, block scan, block-sum scan, add + fill
// ---------------------------------------------------------------------------

__global__ void hist_kernel(const int* __restrict__ ei, int* __restrict__ cnt, int E) {
    int e = blockIdx.x * blockDim.x + threadIdx.x;
    if (e < E) {
        int c = ei[E + e];          // col = edge_index[1]
        atomicAdd(&cnt[c], 1);
    }
}

__global__ void dis_kernel(const int* __restrict__ cnt, float* __restrict__ dis, int n) {
    int v = blockIdx.x * blockDim.x + threadIdx.x;
    if (v < n) {
        // deg = in-degree + 1 (self loop); always >= 1
        dis[v] = rsqrtf((float)(cnt[v] + 1));
    }
}

__global__ void scan1_kernel(const int* __restrict__ cnt, int* __restrict__ offs,
                             int* __restrict__ bsum, int n) {
    __shared__ int s[1024];
    int t = threadIdx.x;
    int v = blockIdx.x * 1024 + t;
    int val = (v < n) ? cnt[v] : 0;
    s[t] = val;
    __syncthreads();
    for (int off = 1; off < 1024; off <<= 1) {
        int add = (t >= off) ? s[t - off] : 0;
        __syncthreads();
        s[t] += add;
        __syncthreads();
    }
    if (v < n) offs[v] = s[t] - val;     // exclusive scan within block
    if (t == 1023) bsum[blockIdx.x] = s[1023];
}

__global__ void scan2_kernel(const int* __restrict__ bsum, int* __restrict__ bscan, int nb) {
    // tiny: single thread sequential scan over nb (~49) block sums
    if (threadIdx.x == 0 && blockIdx.x == 0) {
        int run = 0;
        for (int b = 0; b < nb; b++) { bscan[b] = run; run += bsum[b]; }
        bscan[nb] = run;
    }
}

__global__ void scan3_kernel(int* __restrict__ offs, int* __restrict__ cursor,
                             const int* __restrict__ bscan, int n, int E) {
    int v = blockIdx.x * blockDim.x + threadIdx.x;
    if (v < n) {
        int o = offs[v] + bscan[v >> 10];
        offs[v] = o;
        cursor[v] = o;
    }
    if (v == 0) offs[n] = E;
}

__global__ void fill_kernel(const int* __restrict__ ei, int* __restrict__ cursor,
                            int* __restrict__ srcs, int E) {
    int e = blockIdx.x * blockDim.x + threadIdx.x;
    if (e < E) {
        int r = ei[e];
        int c = ei[E + e];
        int p = atomicAdd(&cursor[c], 1);
        srcs[p] = r;
    }
}

// ---------------------------------------------------------------------------
// GEMM with fused dis-scale epilogue: Y = dis[:,None] * (A @ W)
// A: [n,128] f32, W: [128,128] f32, Y: [n,128] f32
// Block: 256 threads, tile 64 rows x 128 cols, BK=32, each thread 4x8 outputs
// ---------------------------------------------------------------------------

__global__ __launch_bounds__(256) void gemm_scale_kernel(
    const float* __restrict__ A, const float* __restrict__ W,
    const float* __restrict__ dis, float* __restrict__ Y, int n)
{
    __shared__ float As[32][64];    // transposed A tile: As[k][r]
    __shared__ float Bs[32][128];   // Bs[k][c]

    int tid = threadIdx.x;
    int row0 = blockIdx.x * 64;
    int tx = tid & 15;              // 16 col-groups of 8
    int ty = tid >> 4;              // 16 row-groups of 4
    int c0 = tx * 8;
    int r0 = ty * 4;

    float acc[4][8];
#pragma unroll
    for (int i = 0; i < 4; i++)
#pragma unroll
        for (int j = 0; j < 8; j++) acc[i][j] = 0.f;

    for (int kt = 0; kt < 128; kt += 32) {
        // Load A tile (64 rows x 32 cols) transposed into As. 512 float4, 2/thread.
#pragma unroll
        for (int i = 0; i < 2; i++) {
            int idx = i * 256 + tid;      // 0..511
            int r = idx >> 3;             // row within tile
            int kg = idx & 7;             // float4 group within 32-col stripe
            int row = row0 + r;
            float4 a = make_float4(0.f, 0.f, 0.f, 0.f);
            if (row < n) a = *(const float4*)&A[row * HID + kt + kg * 4];
            As[kg * 4 + 0][r] = a.x;
            As[kg * 4 + 1][r] = a.y;
            As[kg * 4 + 2][r] = a.z;
            As[kg * 4 + 3][r] = a.w;
        }
        // Load B tile (32 rows x 128 cols). 1024 float4, 4/thread, coalesced.
#pragma unroll
        for (int i = 0; i < 4; i++) {
            int idx = i * 256 + tid;      // 0..1023
            int r = idx >> 5;
            int cg = idx & 31;
            *(float4*)&Bs[r][cg * 4] = *(const float4*)&W[(kt + r) * HID + cg * 4];
        }
        __syncthreads();

#pragma unroll
        for (int k = 0; k < 32; k++) {
            float4 a4 = *(const float4*)&As[k][r0];
            float4 b4a = *(const float4*)&Bs[k][c0];
            float4 b4b = *(const float4*)&Bs[k][c0 + 4];
            float av[4] = {a4.x, a4.y, a4.z, a4.w};
            float bv[8] = {b4a.x, b4a.y, b4a.z, b4a.w, b4b.x, b4b.y, b4b.z, b4b.w};
#pragma unroll
            for (int i = 0; i < 4; i++)
#pragma unroll
                for (int j = 0; j < 8; j++) acc[i][j] = fmaf(av[i], bv[j], acc[i][j]);
        }
        __syncthreads();
    }

    // Epilogue: scale by dis[row], store
#pragma unroll
    for (int i = 0; i < 4; i++) {
        int row = row0 + r0 + i;
        if (row < n) {
            float d = dis[row];
            float4 o1 = make_float4(acc[i][0] * d, acc[i][1] * d, acc[i][2] * d, acc[i][3] * d);
            float4 o2 = make_float4(acc[i][4] * d, acc[i][5] * d, acc[i][6] * d, acc[i][7] * d);
            *(float4*)&Y[row * HID + c0] = o1;
            *(float4*)&Y[row * HID + c0 + 4] = o2;
        }
    }
}

// ---------------------------------------------------------------------------
// Aggregation: H[v] = relu(dis[v] * (Y[v] + sum_{r in CSR[v]} Y[r]) + b)
// Half-wave (32 lanes x float4) per node.
// ---------------------------------------------------------------------------

__global__ __launch_bounds__(256) void aggregate_kernel(
    const float* __restrict__ Y, const int* __restrict__ offs,
    const int* __restrict__ srcs, const float* __restrict__ dis,
    const float* __restrict__ bias, float* __restrict__ H, int n)
{
    int tid = threadIdx.x;
    int node = blockIdx.x * 8 + (tid >> 5);
    if (node >= n) return;
    int lane = tid & 31;
    int c = lane * 4;

    float4 acc = *(const float4*)&Y[node * HID + c];   // self loop term
    int beg = offs[node];
    int end = offs[node + 1];
    for (int j = beg; j < end; j++) {
        int r = srcs[j];
        float4 v = *(const float4*)&Y[r * HID + c];
        acc.x += v.x; acc.y += v.y; acc.z += v.z; acc.w += v.w;
    }
    float d = dis[node];
    float4 bb = *(const float4*)&bias[c];
    float4 o;
    o.x = fmaxf(fmaf(d, acc.x, bb.x), 0.f);
    o.y = fmaxf(fmaf(d, acc.y, bb.y), 0.f);
    o.z = fmaxf(fmaf(d, acc.z, bb.z), 0.f);
    o.w = fmaxf(fmaf(d, acc.w, bb.w), 0.f);
    *(float4*)&H[node * HID + c] = o;
}

// ---------------------------------------------------------------------------
// Mean-pool: batch is sorted; each half-wave accumulates 16 consecutive nodes
// locally, flushing (atomic) only on graph boundary.
// ---------------------------------------------------------------------------

__global__ __launch_bounds__(256) void pool_kernel(
    const float* __restrict__ H, const int* __restrict__ batch,
    float* __restrict__ gsum, float* __restrict__ gcnt, int n)
{
    int half = blockIdx.x * 8 + (threadIdx.x >> 5);
    int lane = threadIdx.x & 31;
    int c = lane * 4;
    int n0 = half * 16;
    if (n0 >= n) return;
    int n1 = min(n0 + 16, n);

    float4 acc = make_float4(0.f, 0.f, 0.f, 0.f);
    float cntv = 0.f;
    int gprev = batch[n0];
    for (int v = n0; v < n1; v++) {
        int g = batch[v];
        if (g != gprev) {
            atomicAdd(&gsum[gprev * HID + c + 0], acc.x);
            atomicAdd(&gsum[gprev * HID + c + 1], acc.y);
            atomicAdd(&gsum[gprev * HID + c + 2], acc.z);
            atomicAdd(&gsum[gprev * HID + c + 3], acc.w);
            if (lane == 0) atomicAdd(&gcnt[gprev], cntv);
            acc = make_float4(0.f, 0.f, 0.f, 0.f);
            cntv = 0.f;
            gprev = g;
        }
        float4 h = *(const float4*)&H[v * HID + c];
        acc.x += h.x; acc.y += h.y; acc.z += h.z; acc.w += h.w;
        cntv += 1.f;
    }
    atomicAdd(&gsum[gprev * HID + c + 0], acc.x);
    atomicAdd(&gsum[gprev * HID + c + 1], acc.y);
    atomicAdd(&gsum[gprev * HID + c + 2], acc.z);
    atomicAdd(&gsum[gprev * HID + c + 3], acc.w);
    if (lane == 0) atomicAdd(&gcnt[gprev], cntv);
}

// ---------------------------------------------------------------------------
// Classifier: out[g] = (gsum[g]/max(cnt,1)) @ lin_w + lin_b
// ---------------------------------------------------------------------------

__global__ __launch_bounds__(128) void classify_kernel(
    const float* __restrict__ gsum, const float* __restrict__ gcnt,
    const float* __restrict__ lin_w, const float* __restrict__ lin_b,
    float* __restrict__ out)
{
    __shared__ float sp[HID];
    int g = blockIdx.x;
    int f = threadIdx.x;
    float denom = fmaxf(gcnt[g], 1.0f);
    sp[f] = gsum[g * HID + f] / denom;
    __syncthreads();
    if (f < NCLS) {
        float acc = lin_b[f];
        for (int k = 0; k < HID; k++) acc = fmaf(sp[k], lin_w[k * NCLS + f], acc);
        out[g * NCLS + f] = acc;
    }
}

// ---------------------------------------------------------------------------
// Launch
// ---------------------------------------------------------------------------

extern "C" void kernel_launch(void* const* d_in, const int* in_sizes, int n_in,
                              void* d_out, int out_size, void* d_ws, size_t ws_size,
                              hipStream_t stream) {
    const float* x     = (const float*)d_in[0];
    const int*   ei    = (const int*)d_in[1];
    const int*   batch = (const int*)d_in[2];
    const float* W0    = (const float*)d_in[3];
    const float* b0    = (const float*)d_in[4];
    const float* W1    = (const float*)d_in[5];
    const float* b1    = (const float*)d_in[6];
    const float* W2    = (const float*)d_in[7];
    const float* b2    = (const float*)d_in[8];
    const float* lin_w = (const float*)d_in[9];
    const float* lin_b = (const float*)d_in[10];
    float* out = (float*)d_out;

    const int n = in_sizes[0] / HID;      // 50000
    const int E = in_sizes[1] / 2;        // 800000

    // Workspace carve-up (all offsets 256B-aligned)
    char* w = (char*)d_ws;
    auto carve = [&](size_t bytes) {
        void* p = (void*)w;
        w += (bytes + 255) & ~(size_t)255;
        return p;
    };
    int*   cnt    = (int*)carve((size_t)n * 4);
    int*   offs   = (int*)carve(((size_t)n + 1) * 4);
    int*   cursor = (int*)carve((size_t)n * 4);
    int*   bsum   = (int*)carve(256 * 4);
    int*   bscan  = (int*)carve(256 * 4);
    int*   srcs   = (int*)carve((size_t)E * 4);
    float* dis    = (float*)carve((size_t)n * 4);
    float* Y      = (float*)carve((size_t)n * HID * 4);
    float* H      = (float*)carve((size_t)n * HID * 4);
    float* gsum   = (float*)carve((size_t)NGRAPH * HID * 4);
    float* gcnt   = (float*)carve((size_t)NGRAPH * 4);

    // Zero what must be zero (ws is poisoned 0xAA before every call)
    hipMemsetAsync(cnt, 0, (size_t)n * 4, stream);
    hipMemsetAsync(gsum, 0, (size_t)NGRAPH * HID * 4, stream);
    hipMemsetAsync(gcnt, 0, (size_t)NGRAPH * 4, stream);

    const int TB = 256;
    int gE = (E + TB - 1) / TB;           // 3125
    int gN = (n + TB - 1) / TB;           // 196
    int nb1 = (n + 1023) / 1024;          // 49

    hist_kernel<<<gE, TB, 0, stream>>>(ei, cnt, E);
    dis_kernel<<<gN, TB, 0, stream>>>(cnt, dis, n);
    scan1_kernel<<<nb1, 1024, 0, stream>>>(cnt, offs, bsum, n);
    scan2_kernel<<<1, 64, 0, stream>>>(bsum, bscan, nb1);
    scan3_kernel<<<gN, TB, 0, stream>>>(offs, cursor, bscan, n, E);
    fill_kernel<<<gE, TB, 0, stream>>>(ei, cursor, srcs, E);

    int gGemm = (n + 63) / 64;            // 782
    int gAgg  = (n + 7) / 8;              // 6250

    // Layer 1
    gemm_scale_kernel<<<gGemm, TB, 0, stream>>>(x, W0, dis, Y, n);
    aggregate_kernel<<<gAgg, TB, 0, stream>>>(Y, offs, srcs, dis, b0, H, n);
    // Layer 2
    gemm_scale_kernel<<<gGemm, TB, 0, stream>>>(H, W1, dis, Y, n);
    aggregate_kernel<<<gAgg, TB, 0, stream>>>(Y, offs, srcs, dis, b1, H, n);
    // Layer 3
    gemm_scale_kernel<<<gGemm, TB, 0, stream>>>(H, W2, dis, Y, n);
    aggregate_kernel<<<gAgg, TB, 0, stream>>>(Y, offs, srcs, dis, b2, H, n);

    // Pool + classify
    int halves = (n + 15) / 16;
    int gPool = (halves + 7) / 8;
    pool_kernel<<<gPool, TB, 0, stream>>>(H, batch, gsum, gcnt, n);
    classify_kernel<<<NGRAPH, 128, 0, stream>>>(gsum, gcnt, lin_w, lin_b, out);
}

// Round 7
// 486.484 us; speedup vs baseline: 1.0231x; 1.0231x over previous
//
#include <hip/hip_runtime.h>
#include <hip/hip_bf16.h>

// Problem constants (from reference)
#define HID 128
#define NCLS 12
#define NGRAPH 128

// ---------------------------------------------------------------------------
// CSR build: histogram of in-degree, block scan (+ dis), block-sum scan, fill
// ---------------------------------------------------------------------------

__global__ void hist_kernel(const int* __restrict__ ei, int* __restrict__ cnt, int E) {
    int e = blockIdx.x * blockDim.x + threadIdx.x;
    if (e < E) {
        int c = ei[E + e];          // col = edge_index[1]
        atomicAdd(&cnt[c], 1);
    }
}

__global__ void scan1_kernel(const int* __restrict__ cnt, int* __restrict__ offs,
                             int* __restrict__ bsum, float* __restrict__ dis, int n) {
    __shared__ int s[1024];
    int t = threadIdx.x;
    int v = blockIdx.x * 1024 + t;
    int val = (v < n) ? cnt[v] : 0;
    if (v < n) dis[v] = rsqrtf((float)(val + 1));   // deg = in-degree + self loop
    s[t] = val;
    __syncthreads();
    for (int off = 1; off < 1024; off <<= 1) {
        int add = (t >= off) ? s[t - off] : 0;
        __syncthreads();
        s[t] += add;
        __syncthreads();
    }
    if (v < n) offs[v] = s[t] - val;     // exclusive scan within block
    if (t == 1023) bsum[blockIdx.x] = s[1023];
}

__global__ void scan2_kernel(const int* __restrict__ bsum, int* __restrict__ bscan, int nb) {
    if (threadIdx.x == 0 && blockIdx.x == 0) {
        int run = 0;
        for (int b = 0; b < nb; b++) { bscan[b] = run; run += bsum[b]; }
        bscan[nb] = run;
    }
}

__global__ void scan3_kernel(int* __restrict__ offs, int* __restrict__ cursor,
                             const int* __restrict__ bscan, int n, int E) {
    int v = blockIdx.x * blockDim.x + threadIdx.x;
    if (v < n) {
        int o = offs[v] + bscan[v >> 10];
        offs[v] = o;
        cursor[v] = o;
    }
    if (v == 0) offs[n] = E;
}

__global__ void fill_kernel(const int* __restrict__ ei, int* __restrict__ cursor,
                            int* __restrict__ srcs, int E) {
    int e = blockIdx.x * blockDim.x + threadIdx.x;
    if (e < E) {
        int r = ei[e];
        int c = ei[E + e];
        int p = atomicAdd(&cursor[c], 1);
        srcs[p] = r;
    }
}

// ---------------------------------------------------------------------------
// GEMM with fused dis-scale epilogue: Y = dis[:,None] * (A @ W)
// Block: 256 threads, tile 128 rows x 128 cols, BK=16, 8x8 outputs/thread.
// Per-thread cols split as {tx*4 .. +3} and {64+tx*4 .. +3} so LDS reads are
// lane-consecutive float4 (conflict-free). As padded to 132 to break the
// transpose-scatter write conflict.
// ---------------------------------------------------------------------------

__global__ __launch_bounds__(256) void gemm_scale_kernel(
    const float* __restrict__ A, const float* __restrict__ W,
    const float* __restrict__ dis, float* __restrict__ Y, int n)
{
    __shared__ float As[16][132];   // transposed A tile: As[k][r]
    __shared__ float Bs[16][132];   // Bs[k][c]

    int tid = threadIdx.x;
    int row0 = blockIdx.x * 128;
    int tx = tid & 15;              // 16 col groups
    int ty = tid >> 4;              // 16 row groups of 8
    int c0 = tx * 4;                // first col quad; second at c0+64
    int r0 = ty * 8;

    float acc[8][8];
#pragma unroll
    for (int i = 0; i < 8; i++)
#pragma unroll
        for (int j = 0; j < 8; j++) acc[i][j] = 0.f;

    for (int kt = 0; kt < 128; kt += 16) {
        // A tile: 128 rows x 16 cols -> transposed. 512 float4, 2/thread.
#pragma unroll
        for (int i = 0; i < 2; i++) {
            int idx = i * 256 + tid;      // 0..511
            int r = idx >> 2;             // row within tile (0..127)
            int kg = idx & 3;             // float4 group within 16-col stripe
            int row = row0 + r;
            float4 a = make_float4(0.f, 0.f, 0.f, 0.f);
            if (row < n) a = *(const float4*)&A[row * HID + kt + kg * 4];
            As[kg * 4 + 0][r] = a.x;
            As[kg * 4 + 1][r] = a.y;
            As[kg * 4 + 2][r] = a.z;
            As[kg * 4 + 3][r] = a.w;
        }
        // B tile: 16 rows x 128 cols. 512 float4, 2/thread, coalesced.
#pragma unroll
        for (int i = 0; i < 2; i++) {
            int idx = i * 256 + tid;      // 0..511
            int rr = idx >> 5;            // 0..15
            int cg = idx & 31;
            *(float4*)&Bs[rr][cg * 4] = *(const float4*)&W[(kt + rr) * HID + cg * 4];
        }
        __syncthreads();

#pragma unroll
        for (int k = 0; k < 16; k++) {
            float4 a0 = *(const float4*)&As[k][r0];
            float4 a1 = *(const float4*)&As[k][r0 + 4];
            float4 b0 = *(const float4*)&Bs[k][c0];
            float4 b1 = *(const float4*)&Bs[k][c0 + 64];
            float av[8] = {a0.x, a0.y, a0.z, a0.w, a1.x, a1.y, a1.z, a1.w};
            float bv[8] = {b0.x, b0.y, b0.z, b0.w, b1.x, b1.y, b1.z, b1.w};
#pragma unroll
            for (int i = 0; i < 8; i++)
#pragma unroll
                for (int j = 0; j < 8; j++) acc[i][j] = fmaf(av[i], bv[j], acc[i][j]);
        }
        __syncthreads();
    }

    // Epilogue: scale by dis[row], store two float4 per row
#pragma unroll
    for (int i = 0; i < 8; i++) {
        int row = row0 + r0 + i;
        if (row < n) {
            float d = dis[row];
            float4 o1 = make_float4(acc[i][0] * d, acc[i][1] * d, acc[i][2] * d, acc[i][3] * d);
            float4 o2 = make_float4(acc[i][4] * d, acc[i][5] * d, acc[i][6] * d, acc[i][7] * d);
            *(float4*)&Y[row * HID + c0] = o1;
            *(float4*)&Y[row * HID + c0 + 64] = o2;
        }
    }
}

// ---------------------------------------------------------------------------
// Aggregation: H[v] = relu(dis[v] * (Y[v] + sum_{r in CSR[v]} Y[r]) + b)
// Half-wave (32 lanes x float4) per node; 8-way unrolled gather for MLP.
// ---------------------------------------------------------------------------

__global__ __launch_bounds__(256) void aggregate_kernel(
    const float* __restrict__ Y, const int* __restrict__ offs,
    const int* __restrict__ srcs, const float* __restrict__ dis,
    const float* __restrict__ bias, float* __restrict__ H, int n)
{
    int tid = threadIdx.x;
    int node = blockIdx.x * 8 + (tid >> 5);
    if (node >= n) return;
    int lane = tid & 31;
    int c = lane * 4;
    const float* Yc = Y + c;

    float4 a0 = *(const float4*)&Yc[node * HID];   // self loop term
    float4 a1 = make_float4(0.f, 0.f, 0.f, 0.f);
    float4 a2 = make_float4(0.f, 0.f, 0.f, 0.f);
    float4 a3 = make_float4(0.f, 0.f, 0.f, 0.f);
    float4 a4 = make_float4(0.f, 0.f, 0.f, 0.f);
    float4 a5 = make_float4(0.f, 0.f, 0.f, 0.f);
    float4 a6 = make_float4(0.f, 0.f, 0.f, 0.f);
    float4 a7 = make_float4(0.f, 0.f, 0.f, 0.f);

    int beg = offs[node];
    int end = offs[node + 1];
    int j = beg;
    for (; j + 8 <= end; j += 8) {
        int r0 = srcs[j + 0], r1 = srcs[j + 1], r2 = srcs[j + 2], r3 = srcs[j + 3];
        int r4 = srcs[j + 4], r5 = srcs[j + 5], r6 = srcs[j + 6], r7 = srcs[j + 7];
        float4 v0 = *(const float4*)&Yc[r0 * HID];
        float4 v1 = *(const float4*)&Yc[r1 * HID];
        float4 v2 = *(const float4*)&Yc[r2 * HID];
        float4 v3 = *(const float4*)&Yc[r3 * HID];
        float4 v4 = *(const float4*)&Yc[r4 * HID];
        float4 v5 = *(const float4*)&Yc[r5 * HID];
        float4 v6 = *(const float4*)&Yc[r6 * HID];
        float4 v7 = *(const float4*)&Yc[r7 * HID];
        a0.x += v0.x; a0.y += v0.y; a0.z += v0.z; a0.w += v0.w;
        a1.x += v1.x; a1.y += v1.y; a1.z += v1.z; a1.w += v1.w;
        a2.x += v2.x; a2.y += v2.y; a2.z += v2.z; a2.w += v2.w;
        a3.x += v3.x; a3.y += v3.y; a3.z += v3.z; a3.w += v3.w;
        a4.x += v4.x; a4.y += v4.y; a4.z += v4.z; a4.w += v4.w;
        a5.x += v5.x; a5.y += v5.y; a5.z += v5.z; a5.w += v5.w;
        a6.x += v6.x; a6.y += v6.y; a6.z += v6.z; a6.w += v6.w;
        a7.x += v7.x; a7.y += v7.y; a7.z += v7.z; a7.w += v7.w;
    }
    for (; j + 2 <= end; j += 2) {
        int r0 = srcs[j + 0], r1 = srcs[j + 1];
        float4 v0 = *(const float4*)&Yc[r0 * HID];
        float4 v1 = *(const float4*)&Yc[r1 * HID];
        a0.x += v0.x; a0.y += v0.y; a0.z += v0.z; a0.w += v0.w;
        a1.x += v1.x; a1.y += v1.y; a1.z += v1.z; a1.w += v1.w;
    }
    if (j < end) {
        int r0 = srcs[j];
        float4 v0 = *(const float4*)&Yc[r0 * HID];
        a0.x += v0.x; a0.y += v0.y; a0.z += v0.z; a0.w += v0.w;
    }

    a0.x += a1.x + a2.x + a3.x + a4.x + a5.x + a6.x + a7.x;
    a0.y += a1.y + a2.y + a3.y + a4.y + a5.y + a6.y + a7.y;
    a0.z += a1.z + a2.z + a3.z + a4.z + a5.z + a6.z + a7.z;
    a0.w += a1.w + a2.w + a3.w + a4.w + a5.w + a6.w + a7.w;

    float d = dis[node];
    float4 bb = *(const float4*)&bias[c];
    float4 o;
    o.x = fmaxf(fmaf(d, a0.x, bb.x), 0.f);
    o.y = fmaxf(fmaf(d, a0.y, bb.y), 0.f);
    o.z = fmaxf(fmaf(d, a0.z, bb.z), 0.f);
    o.w = fmaxf(fmaf(d, a0.w, bb.w), 0.f);
    *(float4*)&H[node * HID + c] = o;
}

// ---------------------------------------------------------------------------
// Mean-pool: batch is sorted; each half-wave accumulates 16 consecutive nodes
// locally, flushing (atomic) only on graph boundary.
// ---------------------------------------------------------------------------

__global__ __launch_bounds__(256) void pool_kernel(
    const float* __restrict__ H, const int* __restrict__ batch,
    float* __restrict__ gsum, float* __restrict__ gcnt, int n)
{
    int half = blockIdx.x * 8 + (threadIdx.x >> 5);
    int lane = threadIdx.x & 31;
    int c = lane * 4;
    int n0 = half * 16;
    if (n0 >= n) return;
    int n1 = min(n0 + 16, n);

    float4 acc = make_float4(0.f, 0.f, 0.f, 0.f);
    float cntv = 0.f;
    int gprev = batch[n0];
    for (int v = n0; v < n1; v++) {
        int g = batch[v];
        if (g != gprev) {
            atomicAdd(&gsum[gprev * HID + c + 0], acc.x);
            atomicAdd(&gsum[gprev * HID + c + 1], acc.y);
            atomicAdd(&gsum[gprev * HID + c + 2], acc.z);
            atomicAdd(&gsum[gprev * HID + c + 3], acc.w);
            if (lane == 0) atomicAdd(&gcnt[gprev], cntv);
            acc = make_float4(0.f, 0.f, 0.f, 0.f);
            cntv = 0.f;
            gprev = g;
        }
        float4 h = *(const float4*)&H[v * HID + c];
        acc.x += h.x; acc.y += h.y; acc.z += h.z; acc.w += h.w;
        cntv += 1.f;
    }
    atomicAdd(&gsum[gprev * HID + c + 0], acc.x);
    atomicAdd(&gsum[gprev * HID + c + 1], acc.y);
    atomicAdd(&gsum[gprev * HID + c + 2], acc.z);
    atomicAdd(&gsum[gprev * HID + c + 3], acc.w);
    if (lane == 0) atomicAdd(&gcnt[gprev], cntv);
}

// ---------------------------------------------------------------------------
// Classifier: out[g] = (gsum[g]/max(cnt,1)) @ lin_w + lin_b
// ---------------------------------------------------------------------------

__global__ __launch_bounds__(128) void classify_kernel(
    const float* __restrict__ gsum, const float* __restrict__ gcnt,
    const float* __restrict__ lin_w, const float* __restrict__ lin_b,
    float* __restrict__ out)
{
    __shared__ float sp[HID];
    int g = blockIdx.x;
    int f = threadIdx.x;
    float denom = fmaxf(gcnt[g], 1.0f);
    sp[f] = gsum[g * HID + f] / denom;
    __syncthreads();
    if (f < NCLS) {
        float acc = lin_b[f];
        for (int k = 0; k < HID; k++) acc = fmaf(sp[k], lin_w[k * NCLS + f], acc);
        out[g * NCLS + f] = acc;
    }
}

// ---------------------------------------------------------------------------
// Launch
// ---------------------------------------------------------------------------

extern "C" void kernel_launch(void* const* d_in, const int* in_sizes, int n_in,
                              void* d_out, int out_size, void* d_ws, size_t ws_size,
                              hipStream_t stream) {
    const float* x     = (const float*)d_in[0];
    const int*   ei    = (const int*)d_in[1];
    const int*   batch = (const int*)d_in[2];
    const float* W0    = (const float*)d_in[3];
    const float* b0    = (const float*)d_in[4];
    const float* W1    = (const float*)d_in[5];
    const float* b1    = (const float*)d_in[6];
    const float* W2    = (const float*)d_in[7];
    const float* b2    = (const float*)d_in[8];
    const float* lin_w = (const float*)d_in[9];
    const float* lin_b = (const float*)d_in[10];
    float* out = (float*)d_out;

    const int n = in_sizes[0] / HID;      // 50000
    const int E = in_sizes[1] / 2;        // 800000

    // Workspace carve-up (all offsets 256B-aligned)
    char* w = (char*)d_ws;
    auto carve = [&](size_t bytes) {
        void* p = (void*)w;
        w += (bytes + 255) & ~(size_t)255;
        return p;
    };
    int*   cnt    = (int*)carve((size_t)n * 4);
    int*   offs   = (int*)carve(((size_t)n + 1) * 4);
    int*   cursor = (int*)carve((size_t)n * 4);
    int*   bsum   = (int*)carve(256 * 4);
    int*   bscan  = (int*)carve(256 * 4);
    int*   srcs   = (int*)carve((size_t)E * 4);
    float* dis    = (float*)carve((size_t)n * 4);
    float* Y      = (float*)carve((size_t)n * HID * 4);
    float* H      = (float*)carve((size_t)n * HID * 4);
    float* gsum   = (float*)carve((size_t)NGRAPH * HID * 4);
    float* gcnt   = (float*)carve((size_t)NGRAPH * 4);

    hipMemsetAsync(cnt, 0, (size_t)n * 4, stream);
    hipMemsetAsync(gsum, 0, (size_t)NGRAPH * HID * 4, stream);
    hipMemsetAsync(gcnt, 0, (size_t)NGRAPH * 4, stream);

    const int TB = 256;
    int gE = (E + TB - 1) / TB;           // 3125
    int gN = (n + TB - 1) / TB;           // 196
    int nb1 = (n + 1023) / 1024;          // 49

    hist_kernel<<<gE, TB, 0, stream>>>(ei, cnt, E);
    scan1_kernel<<<nb1, 1024, 0, stream>>>(cnt, offs, bsum, dis, n);
    scan2_kernel<<<1, 64, 0, stream>>>(bsum, bscan, nb1);
    scan3_kernel<<<gN, TB, 0, stream>>>(offs, cursor, bscan, n, E);
    fill_kernel<<<gE, TB, 0, stream>>>(ei, cursor, srcs, E);

    int gGemm = (n + 127) / 128;          // 391
    int gAgg  = (n + 7) / 8;              // 6250

    // Layer 1
    gemm_scale_kernel<<<gGemm, TB, 0, stream>>>(x, W0, dis, Y, n);
    aggregate_kernel<<<gAgg, TB, 0, stream>>>(Y, offs, srcs, dis, b0, H, n);
    // Layer 2
    gemm_scale_kernel<<<gGemm, TB, 0, stream>>>(H, W1, dis, Y, n);
    aggregate_kernel<<<gAgg, TB, 0, stream>>>(Y, offs, srcs, dis, b1, H, n);
    // Layer 3
    gemm_scale_kernel<<<gGemm, TB, 0, stream>>>(H, W2, dis, Y, n);
    aggregate_kernel<<<gAgg, TB, 0, stream>>>(Y, offs, srcs, dis, b2, H, n);

    // Pool + classify
    int halves = (n + 15) / 16;
    int gPool = (halves + 7) / 8;
    pool_kernel<<<gPool, TB, 0, stream>>>(H, batch, gsum, gcnt, n);
    classify_kernel<<<NGRAPH, 128, 0, stream>>>(gsum, gcnt, lin_w, lin_b, out);
}

// Round 9
// 377.031 us; speedup vs baseline: 1.3201x; 1.2903x over previous
//
#include <hip/hip_runtime.h>
#include <hip/hip_bf16.h>

// Problem constants (from reference)
#define HID 128
#define NCLS 12
#define NGRAPH 128

typedef __attribute__((ext_vector_type(8))) short short8v;   // 8 bf16 (4 VGPRs)
typedef __attribute__((ext_vector_type(4))) float float4v;   // 4 f32 accum

// f32 -> bf16 round-to-nearest-even (bit manipulation; data is finite)
__device__ __forceinline__ ushort f2bf(float f) {
    uint u = __float_as_uint(f);
    u += 0x7FFFu + ((u >> 16) & 1u);
    return (ushort)(u >> 16);
}
__device__ __forceinline__ float bf2f(ushort u) {
    return __uint_as_float(((uint)u) << 16);
}
__device__ __forceinline__ float4 bf4tof(ushort4 u) {
    float4 f;
    f.x = bf2f(u.x); f.y = bf2f(u.y); f.z = bf2f(u.z); f.w = bf2f(u.w);
    return f;
}

// ---------------------------------------------------------------------------
// CSR build: histogram of in-degree, block scan (+ dis), block-sum scan, fill
// ---------------------------------------------------------------------------

__global__ void hist_kernel(const int* __restrict__ ei, int* __restrict__ cnt, int E) {
    int e = blockIdx.x * blockDim.x + threadIdx.x;
    if (e < E) {
        int c = ei[E + e];          // col = edge_index[1]
        atomicAdd(&cnt[c], 1);
    }
}

__global__ void scan1_kernel(const int* __restrict__ cnt, int* __restrict__ offs,
                             int* __restrict__ bsum, float* __restrict__ dis, int n) {
    __shared__ int s[1024];
    int t = threadIdx.x;
    int v = blockIdx.x * 1024 + t;
    int val = (v < n) ? cnt[v] : 0;
    if (v < n) dis[v] = rsqrtf((float)(val + 1));   // deg = in-degree + self loop
    s[t] = val;
    __syncthreads();
    for (int off = 1; off < 1024; off <<= 1) {
        int add = (t >= off) ? s[t - off] : 0;
        __syncthreads();
        s[t] += add;
        __syncthreads();
    }
    if (v < n) offs[v] = s[t] - val;     // exclusive scan within block
    if (t == 1023) bsum[blockIdx.x] = s[1023];
}

__global__ void scan2_kernel(const int* __restrict__ bsum, int* __restrict__ bscan, int nb) {
    if (threadIdx.x == 0 && blockIdx.x == 0) {
        int run = 0;
        for (int b = 0; b < nb; b++) { bscan[b] = run; run += bsum[b]; }
        bscan[nb] = run;
    }
}

__global__ void scan3_kernel(int* __restrict__ offs, int* __restrict__ cursor,
                             const int* __restrict__ bscan, int n, int E) {
    int v = blockIdx.x * blockDim.x + threadIdx.x;
    if (v < n) {
        int o = offs[v] + bscan[v >> 10];
        offs[v] = o;
        cursor[v] = o;
    }
    if (v == 0) offs[n] = E;
}

__global__ void fill_kernel(const int* __restrict__ ei, int* __restrict__ cursor,
                            int* __restrict__ srcs, int E) {
    int e = blockIdx.x * blockDim.x + threadIdx.x;
    if (e < E) {
        int r = ei[e];
        int c = ei[E + e];
        int p = atomicAdd(&cursor[c], 1);
        srcs[p] = r;
    }
}

// ---------------------------------------------------------------------------
// Conversions: x f32 -> bf16; W f32 [k][c] -> bf16 transposed Wt[c][k]
// ---------------------------------------------------------------------------

__global__ void cvtx_kernel(const float* __restrict__ x, ushort* __restrict__ xb, int total) {
    int i = (blockIdx.x * blockDim.x + threadIdx.x) * 4;
    if (i < total) {
        float4 v = *(const float4*)&x[i];
        ushort4 o;
        o.x = f2bf(v.x); o.y = f2bf(v.y); o.z = f2bf(v.z); o.w = f2bf(v.w);
        *(ushort4*)&xb[i] = o;
    }
}

__global__ void cvtw_kernel(const float* __restrict__ W, ushort* __restrict__ Wt) {
    int idx = blockIdx.x * 256 + threadIdx.x;   // 16384 elems, grid=64
    int k = idx >> 7;
    int c = idx & 127;
    Wt[c * HID + k] = f2bf(W[k * HID + c]);
}

// ---------------------------------------------------------------------------
// bf16 MFMA GEMM with fused dis-scale: Y = bf16( dis[:,None] * (A @ W) )
// A: [n][128] bf16 row-major. Wt: [c][k] bf16 (= W transposed).
// 256 threads = 4 waves; block covers 128 rows; wave covers 32 rows x 128 cols.
// mfma_f32_16x16x32_bf16 with SWAPPED operands: acc = mfma(w_frag, a_frag, acc)
//   => lane holds Y[row = rowbase + m*16 + (lane&15)]
//                [cols = nn*16 + (lane>>4)*4 + r], r=0..3  -> ushort4 store.
// Operand layouts (guide §3, m89-verified):
//   "A"-operand (w_frag): lane = Wt[nn*16 + (lane&15)][kk*32 + (lane>>4)*8 ..+7]
//   "B"-operand (a_frag): lane = A [rowbase+m*16+(lane&15)][kk*32 + (lane>>4)*8 ..+7]
// Both are contiguous 16B loads from global (no LDS needed; Wt is L1/L2-hot).
// ---------------------------------------------------------------------------

__global__ __launch_bounds__(256) void gemm_bf16_kernel(
    const ushort* __restrict__ A, const ushort* __restrict__ Wt,
    const float* __restrict__ dis, ushort* __restrict__ Y, int n)
{
    int tid  = threadIdx.x;
    int wave = tid >> 6;
    int lane = tid & 63;
    int l15  = lane & 15;
    int lg   = lane >> 4;                 // 0..3
    int rowbase = blockIdx.x * 128 + wave * 32;

    float4v acc[2][8];
#pragma unroll
    for (int m = 0; m < 2; m++)
#pragma unroll
        for (int nn = 0; nn < 8; nn++)
            acc[m][nn] = (float4v){0.f, 0.f, 0.f, 0.f};

#pragma unroll
    for (int kk = 0; kk < 4; kk++) {
        int k0 = kk * 32 + lg * 8;
        short8v a[2];
#pragma unroll
        for (int m = 0; m < 2; m++) {
            int row = rowbase + m * 16 + l15;
            if (row < n) a[m] = *(const short8v*)&A[row * HID + k0];
            else         a[m] = (short8v){0,0,0,0,0,0,0,0};
        }
        short8v b[8];
#pragma unroll
        for (int nn = 0; nn < 8; nn++)
            b[nn] = *(const short8v*)&Wt[(nn * 16 + l15) * HID + k0];
#pragma unroll
        for (int m = 0; m < 2; m++)
#pragma unroll
            for (int nn = 0; nn < 8; nn++)
                acc[m][nn] = __builtin_amdgcn_mfma_f32_16x16x32_bf16(
                    b[nn], a[m], acc[m][nn], 0, 0, 0);
    }

    // Epilogue: scale by dis[row], convert, ushort4 (4 consecutive cols) store
#pragma unroll
    for (int m = 0; m < 2; m++) {
        int row = rowbase + m * 16 + l15;
        if (row < n) {
            float d = dis[row];
#pragma unroll
            for (int nn = 0; nn < 8; nn++) {
                ushort4 o;
                o.x = f2bf(acc[m][nn][0] * d);
                o.y = f2bf(acc[m][nn][1] * d);
                o.z = f2bf(acc[m][nn][2] * d);
                o.w = f2bf(acc[m][nn][3] * d);
                *(ushort4*)&Y[row * HID + nn * 16 + lg * 4] = o;
            }
        }
    }
}

// ---------------------------------------------------------------------------
// Aggregation (bf16 in/out, f32 accum):
// H[v] = bf16( relu(dis[v] * (Y[v] + sum_{r in CSR[v]} Y[r]) + b) )
// Half-wave (32 lanes x ushort4 = full 256B row) per node; 8-way unroll.
// ---------------------------------------------------------------------------

__global__ __launch_bounds__(256) void aggregate_bf16_kernel(
    const ushort* __restrict__ Y, const int* __restrict__ offs,
    const int* __restrict__ srcs, const float* __restrict__ dis,
    const float* __restrict__ bias, ushort* __restrict__ H, int n)
{
    int tid = threadIdx.x;
    int node = blockIdx.x * 8 + (tid >> 5);
    if (node >= n) return;
    int lane = tid & 31;
    int c = lane * 4;
    const ushort* Yc = Y + c;

    float4 a0 = bf4tof(*(const ushort4*)&Yc[node * HID]);   // self loop
    float4 a1 = make_float4(0.f, 0.f, 0.f, 0.f);
    float4 a2 = make_float4(0.f, 0.f, 0.f, 0.f);
    float4 a3 = make_float4(0.f, 0.f, 0.f, 0.f);
    float4 a4 = make_float4(0.f, 0.f, 0.f, 0.f);
    float4 a5 = make_float4(0.f, 0.f, 0.f, 0.f);
    float4 a6 = make_float4(0.f, 0.f, 0.f, 0.f);
    float4 a7 = make_float4(0.f, 0.f, 0.f, 0.f);

    int beg = offs[node];
    int end = offs[node + 1];
    int j = beg;
    for (; j + 8 <= end; j += 8) {
        int r0 = srcs[j + 0], r1 = srcs[j + 1], r2 = srcs[j + 2], r3 = srcs[j + 3];
        int r4 = srcs[j + 4], r5 = srcs[j + 5], r6 = srcs[j + 6], r7 = srcs[j + 7];
        float4 v0 = bf4tof(*(const ushort4*)&Yc[r0 * HID]);
        float4 v1 = bf4tof(*(const ushort4*)&Yc[r1 * HID]);
        float4 v2 = bf4tof(*(const ushort4*)&Yc[r2 * HID]);
        float4 v3 = bf4tof(*(const ushort4*)&Yc[r3 * HID]);
        float4 v4 = bf4tof(*(const ushort4*)&Yc[r4 * HID]);
        float4 v5 = bf4tof(*(const ushort4*)&Yc[r5 * HID]);
        float4 v6 = bf4tof(*(const ushort4*)&Yc[r6 * HID]);
        float4 v7 = bf4tof(*(const ushort4*)&Yc[r7 * HID]);
        a0.x += v0.x; a0.y += v0.y; a0.z += v0.z; a0.w += v0.w;
        a1.x += v1.x; a1.y += v1.y; a1.z += v1.z; a1.w += v1.w;
        a2.x += v2.x; a2.y += v2.y; a2.z += v2.z; a2.w += v2.w;
        a3.x += v3.x; a3.y += v3.y; a3.z += v3.z; a3.w += v3.w;
        a4.x += v4.x; a4.y += v4.y; a4.z += v4.z; a4.w += v4.w;
        a5.x += v5.x; a5.y += v5.y; a5.z += v5.z; a5.w += v5.w;
        a6.x += v6.x; a6.y += v6.y; a6.z += v6.z; a6.w += v6.w;
        a7.x += v7.x; a7.y += v7.y; a7.z += v7.z; a7.w += v7.w;
    }
    for (; j + 2 <= end; j += 2) {
        int r0 = srcs[j + 0], r1 = srcs[j + 1];
        float4 v0 = bf4tof(*(const ushort4*)&Yc[r0 * HID]);
        float4 v1 = bf4tof(*(const ushort4*)&Yc[r1 * HID]);
        a0.x += v0.x; a0.y += v0.y; a0.z += v0.z; a0.w += v0.w;
        a1.x += v1.x; a1.y += v1.y; a1.z += v1.z; a1.w += v1.w;
    }
    if (j < end) {
        int r0 = srcs[j];
        float4 v0 = bf4tof(*(const ushort4*)&Yc[r0 * HID]);
        a0.x += v0.x; a0.y += v0.y; a0.z += v0.z; a0.w += v0.w;
    }

    a0.x += a1.x + a2.x + a3.x + a4.x + a5.x + a6.x + a7.x;
    a0.y += a1.y + a2.y + a3.y + a4.y + a5.y + a6.y + a7.y;
    a0.z += a1.z + a2.z + a3.z + a4.z + a5.z + a6.z + a7.z;
    a0.w += a1.w + a2.w + a3.w + a4.w + a5.w + a6.w + a7.w;

    float d = dis[node];
    float4 bb = *(const float4*)&bias[c];
    ushort4 o;
    o.x = f2bf(fmaxf(fmaf(d, a0.x, bb.x), 0.f));
    o.y = f2bf(fmaxf(fmaf(d, a0.y, bb.y), 0.f));
    o.z = f2bf(fmaxf(fmaf(d, a0.z, bb.z), 0.f));
    o.w = f2bf(fmaxf(fmaf(d, a0.w, bb.w), 0.f));
    *(ushort4*)&H[node * HID + c] = o;
}

// ---------------------------------------------------------------------------
// Mean-pool (bf16 input): batch sorted; half-wave accumulates 16 consecutive
// nodes locally in f32, flushing (atomic) only on graph boundary.
// ---------------------------------------------------------------------------

__global__ __launch_bounds__(256) void pool_kernel(
    const ushort* __restrict__ H, const int* __restrict__ batch,
    float* __restrict__ gsum, float* __restrict__ gcnt, int n)
{
    int half = blockIdx.x * 8 + (threadIdx.x >> 5);
    int lane = threadIdx.x & 31;
    int c = lane * 4;
    int n0 = half * 16;
    if (n0 >= n) return;
    int n1 = min(n0 + 16, n);

    float4 acc = make_float4(0.f, 0.f, 0.f, 0.f);
    float cntv = 0.f;
    int gprev = batch[n0];
    for (int v = n0; v < n1; v++) {
        int g = batch[v];
        if (g != gprev) {
            atomicAdd(&gsum[gprev * HID + c + 0], acc.x);
            atomicAdd(&gsum[gprev * HID + c + 1], acc.y);
            atomicAdd(&gsum[gprev * HID + c + 2], acc.z);
            atomicAdd(&gsum[gprev * HID + c + 3], acc.w);
            if (lane == 0) atomicAdd(&gcnt[gprev], cntv);
            acc = make_float4(0.f, 0.f, 0.f, 0.f);
            cntv = 0.f;
            gprev = g;
        }
        float4 h = bf4tof(*(const ushort4*)&H[v * HID + c]);
        acc.x += h.x; acc.y += h.y; acc.z += h.z; acc.w += h.w;
        cntv += 1.f;
    }
    atomicAdd(&gsum[gprev * HID + c + 0], acc.x);
    atomicAdd(&gsum[gprev * HID + c + 1], acc.y);
    atomicAdd(&gsum[gprev * HID + c + 2], acc.z);
    atomicAdd(&gsum[gprev * HID + c + 3], acc.w);
    if (lane == 0) atomicAdd(&gcnt[gprev], cntv);
}

// ---------------------------------------------------------------------------
// Classifier: out[g] = (gsum[g]/max(cnt,1)) @ lin_w + lin_b   (all f32)
// ---------------------------------------------------------------------------

__global__ __launch_bounds__(128) void classify_kernel(
    const float* __restrict__ gsum, const float* __restrict__ gcnt,
    const float* __restrict__ lin_w, const float* __restrict__ lin_b,
    float* __restrict__ out)
{
    __shared__ float sp[HID];
    int g = blockIdx.x;
    int f = threadIdx.x;
    float denom = fmaxf(gcnt[g], 1.0f);
    sp[f] = gsum[g * HID + f] / denom;
    __syncthreads();
    if (f < NCLS) {
        float acc = lin_b[f];
        for (int k = 0; k < HID; k++) acc = fmaf(sp[k], lin_w[k * NCLS + f], acc);
        out[g * NCLS + f] = acc;
    }
}

// ---------------------------------------------------------------------------
// Launch
// ---------------------------------------------------------------------------

extern "C" void kernel_launch(void* const* d_in, const int* in_sizes, int n_in,
                              void* d_out, int out_size, void* d_ws, size_t ws_size,
                              hipStream_t stream) {
    const float* x     = (const float*)d_in[0];
    const int*   ei    = (const int*)d_in[1];
    const int*   batch = (const int*)d_in[2];
    const float* W0    = (const float*)d_in[3];
    const float* b0    = (const float*)d_in[4];
    const float* W1    = (const float*)d_in[5];
    const float* b1    = (const float*)d_in[6];
    const float* W2    = (const float*)d_in[7];
    const float* b2    = (const float*)d_in[8];
    const float* lin_w = (const float*)d_in[9];
    const float* lin_b = (const float*)d_in[10];
    float* out = (float*)d_out;

    const int n = in_sizes[0] / HID;      // 50000
    const int E = in_sizes[1] / 2;        // 800000

    // Workspace carve-up (all offsets 256B-aligned)
    char* w = (char*)d_ws;
    auto carve = [&](size_t bytes) {
        void* p = (void*)w;
        w += (bytes + 255) & ~(size_t)255;
        return p;
    };
    int*    cnt    = (int*)carve((size_t)n * 4);
    int*    offs   = (int*)carve(((size_t)n + 1) * 4);
    int*    cursor = (int*)carve((size_t)n * 4);
    int*    bsum   = (int*)carve(256 * 4);
    int*    bscan  = (int*)carve(256 * 4);
    int*    srcs   = (int*)carve((size_t)E * 4);
    float*  dis    = (float*)carve((size_t)n * 4);
    ushort* xb     = (ushort*)carve((size_t)n * HID * 2);
    ushort* Wt0    = (ushort*)carve((size_t)HID * HID * 2);
    ushort* Wt1    = (ushort*)carve((size_t)HID * HID * 2);
    ushort* Wt2    = (ushort*)carve((size_t)HID * HID * 2);
    ushort* Y      = (ushort*)carve((size_t)n * HID * 2);
    ushort* Hb     = (ushort*)carve((size_t)n * HID * 2);
    float*  gsum   = (float*)carve((size_t)NGRAPH * HID * 4);
    float*  gcnt   = (float*)carve((size_t)NGRAPH * 4);

    hipMemsetAsync(cnt, 0, (size_t)n * 4, stream);
    hipMemsetAsync(gsum, 0, (size_t)NGRAPH * HID * 4, stream);
    hipMemsetAsync(gcnt, 0, (size_t)NGRAPH * 4, stream);

    const int TB = 256;
    int gE = (E + TB - 1) / TB;           // 3125
    int gN = (n + TB - 1) / TB;           // 196
    int nb1 = (n + 1023) / 1024;          // 49

    // CSR build
    hist_kernel<<<gE, TB, 0, stream>>>(ei, cnt, E);
    scan1_kernel<<<nb1, 1024, 0, stream>>>(cnt, offs, bsum, dis, n);
    scan2_kernel<<<1, 64, 0, stream>>>(bsum, bscan, nb1);
    scan3_kernel<<<gN, TB, 0, stream>>>(offs, cursor, bscan, n, E);
    fill_kernel<<<gE, TB, 0, stream>>>(ei, cursor, srcs, E);

    // dtype conversions
    int totalx = n * HID;
    cvtx_kernel<<<(totalx / 4 + TB - 1) / TB, TB, 0, stream>>>(x, xb, totalx);
    cvtw_kernel<<<64, 256, 0, stream>>>(W0, Wt0);
    cvtw_kernel<<<64, 256, 0, stream>>>(W1, Wt1);
    cvtw_kernel<<<64, 256, 0, stream>>>(W2, Wt2);

    int gGemm = (n + 127) / 128;          // 391
    int gAgg  = (n + 7) / 8;              // 6250

    // Layer 1
    gemm_bf16_kernel<<<gGemm, TB, 0, stream>>>(xb, Wt0, dis, Y, n);
    aggregate_bf16_kernel<<<gAgg, TB, 0, stream>>>(Y, offs, srcs, dis, b0, Hb, n);
    // Layer 2
    gemm_bf16_kernel<<<gGemm, TB, 0, stream>>>(Hb, Wt1, dis, Y, n);
    aggregate_bf16_kernel<<<gAgg, TB, 0, stream>>>(Y, offs, srcs, dis, b1, Hb, n);
    // Layer 3
    gemm_bf16_kernel<<<gGemm, TB, 0, stream>>>(Hb, Wt2, dis, Y, n);
    aggregate_bf16_kernel<<<gAgg, TB, 0, stream>>>(Y, offs, srcs, dis, b2, Hb, n);

    // Pool + classify
    int halves = (n + 15) / 16;
    int gPool = (halves + 7) / 8;
    pool_kernel<<<gPool, TB, 0, stream>>>(Hb, batch, gsum, gcnt, n);
    classify_kernel<<<NGRAPH, 128, 0, stream>>>(gsum, gcnt, lin_w, lin_b, out);
}

// Round 13
// 325.191 us; speedup vs baseline: 1.5306x; 1.1594x over previous
//
#include <hip/hip_runtime.h>
#include <hip/hip_bf16.h>

// Problem constants (from reference)
#define HID 128
#define NCLS 12
#define NGRAPH 128
#define EPB 4096   // edges per section in the bucketed counting sort

typedef __attribute__((ext_vector_type(8))) short short8v;   // 8 bf16 (4 VGPRs)
typedef __attribute__((ext_vector_type(4))) float float4v;   // 4 f32 accum

// f32 -> bf16 round-to-nearest-even (bit manipulation; data is finite)
__device__ __forceinline__ ushort f2bf(float f) {
    uint u = __float_as_uint(f);
    u += 0x7FFFu + ((u >> 16) & 1u);
    return (ushort)(u >> 16);
}
__device__ __forceinline__ float bf2f(ushort u) {
    return __uint_as_float(((uint)u) << 16);
}
__device__ __forceinline__ float4 bf4tof(ushort4 u) {
    float4 f;
    f.x = bf2f(u.x); f.y = bf2f(u.y); f.z = bf2f(u.z); f.w = bf2f(u.w);
    return f;
}

// ---------------------------------------------------------------------------
// CSR build, pass 1: partition edges into per-section bucket-sorted order.
// Section k = edges [k*EPB, (k+1)*EPB). Bucket b = dests [b*256, (b+1)*256).
// Writes are SECTION-LOCAL (each block owns a contiguous 32KB region of
// `part`), so no cross-XCD dirty-line bouncing (the old fill_kernel's
// 52MB WRITE_SIZE pathology: one 64B writeback per 4B scatter).
// Outputs: part (r,c pairs, bucket-sorted within section),
//          lscan[k][b] = exclusive scan of section-k bucket counts,
//          btot[b] += section-k count (global bucket totals).
// ---------------------------------------------------------------------------

__global__ __launch_bounds__(256) void part_kernel(
    const int* __restrict__ ei, int2* __restrict__ part,
    int* __restrict__ lscan, int* __restrict__ btot, int E, int nb)
{
    __shared__ int h[256], sc[256], cur[256];
    int k = blockIdx.x;
    int t = threadIdx.x;
    int e0 = k * EPB, e1 = min(e0 + EPB, E);

    h[t] = 0;
    __syncthreads();
    for (int e = e0 + t; e < e1; e += 256)
        atomicAdd(&h[ei[E + e] >> 8], 1);
    __syncthreads();

    sc[t] = h[t];
    __syncthreads();
    for (int off = 1; off < 256; off <<= 1) {
        int add = (t >= off) ? sc[t - off] : 0;
        __syncthreads();
        sc[t] += add;
        __syncthreads();
    }
    int excl = sc[t] - h[t];          // exclusive scan
    cur[t] = excl;
    if (t < nb) {
        lscan[k * (nb + 1) + t] = excl;
        if (h[t] > 0) atomicAdd(&btot[t], h[t]);
    }
    if (t == 0) lscan[k * (nb + 1) + nb] = e1 - e0;
    __syncthreads();

    for (int e = e0 + t; e < e1; e += 256) {
        int r = ei[e], c = ei[E + e];
        int lr = atomicAdd(&cur[c >> 8], 1);
        part[e0 + lr] = make_int2(r, c);
    }
}

// ---------------------------------------------------------------------------
// CSR build, pass 1b: exclusive scan of bucket totals -> gstart[nb+1]
// ---------------------------------------------------------------------------

__global__ void gscan_kernel(const int* __restrict__ btot, int* __restrict__ gstart,
                             int nb, int E) {
    __shared__ int sc[256];
    int t = threadIdx.x;
    int v = (t < nb) ? btot[t] : 0;
    sc[t] = v;
    __syncthreads();
    for (int off = 1; off < 256; off <<= 1) {
        int add = (t >= off) ? sc[t - off] : 0;
        __syncthreads();
        sc[t] += add;
        __syncthreads();
    }
    if (t < nb) gstart[t] = sc[t] - v;
    if (t == 0) gstart[nb] = E;
}

// ---------------------------------------------------------------------------
// CSR build, pass 2: one block per bucket (256 dests). Gather the bucket's
// edges from all sections via lscan; LDS-count + LDS-scan -> offs/dis; fill
// srcs via LDS cursors. All srcs writes land in this block's exclusive
// ~16KB CSR region -> L2-local, full-line writebacks.
// ---------------------------------------------------------------------------

__global__ __launch_bounds__(256) void csr_kernel(
    const int2* __restrict__ part, const int* __restrict__ lscan,
    const int* __restrict__ gstart, int* __restrict__ offs,
    int* __restrict__ srcs, float* __restrict__ dis,
    int n, int E, int nb, int nsec)
{
    __shared__ int cnt[256], sc[256], cur[256];
    int b = blockIdx.x, t = threadIdx.x;

    cnt[t] = 0;
    __syncthreads();
    // Phase A: count this bucket's dests (thread t owns section t, t+256, ...)
    for (int k = t; k < nsec; k += 256) {
        const int* lrow = &lscan[k * (nb + 1)];
        int s0 = lrow[b], s1 = lrow[b + 1];
        int base = k * EPB;
        for (int e = s0; e < s1; e++) {
            int2 pr = part[base + e];
            atomicAdd(&cnt[pr.y & 255], 1);
        }
    }
    __syncthreads();

    // Phase B: scan counts; write offs, dis; init cursors
    sc[t] = cnt[t];
    __syncthreads();
    for (int off = 1; off < 256; off <<= 1) {
        int add = (t >= off) ? sc[t - off] : 0;
        __syncthreads();
        sc[t] += add;
        __syncthreads();
    }
    int excl = sc[t] - cnt[t];
    int g0 = gstart[b];
    int d = b * 256 + t;
    if (d < n) {
        offs[d] = g0 + excl;
        dis[d] = rsqrtf((float)(cnt[t] + 1));   // deg = in-degree + self loop
    }
    cur[t] = g0 + excl;
    if (b == nb - 1 && t == 0) offs[n] = E;
    __syncthreads();

    // Phase C: fill srcs (part re-read is L2-hot from Phase A)
    for (int k = t; k < nsec; k += 256) {
        const int* lrow = &lscan[k * (nb + 1)];
        int s0 = lrow[b], s1 = lrow[b + 1];
        int base = k * EPB;
        for (int e = s0; e < s1; e++) {
            int2 pr = part[base + e];
            int p = atomicAdd(&cur[pr.y & 255], 1);
            srcs[p] = pr.x;
        }
    }
}

// ---------------------------------------------------------------------------
// Conversions: x f32 -> bf16; W f32 [k][c] -> bf16 transposed Wt[c][k]
// ---------------------------------------------------------------------------

__global__ void cvtx_kernel(const float* __restrict__ x, ushort* __restrict__ xb, int total) {
    int i = (blockIdx.x * blockDim.x + threadIdx.x) * 4;
    if (i < total) {
        float4 v = *(const float4*)&x[i];
        ushort4 o;
        o.x = f2bf(v.x); o.y = f2bf(v.y); o.z = f2bf(v.z); o.w = f2bf(v.w);
        *(ushort4*)&xb[i] = o;
    }
}

__global__ void cvtw_kernel(const float* __restrict__ W, ushort* __restrict__ Wt) {
    int idx = blockIdx.x * 256 + threadIdx.x;   // 16384 elems, grid=64
    int k = idx >> 7;
    int c = idx & 127;
    Wt[c * HID + k] = f2bf(W[k * HID + c]);
}

// ---------------------------------------------------------------------------
// bf16 MFMA GEMM with fused dis-scale: Y = bf16( dis[:,None] * (A @ W) )
// (unchanged from round 7 — verified passing, absmax 9.8e-4)
// ---------------------------------------------------------------------------

__global__ __launch_bounds__(256) void gemm_bf16_kernel(
    const ushort* __restrict__ A, const ushort* __restrict__ Wt,
    const float* __restrict__ dis, ushort* __restrict__ Y, int n)
{
    int tid  = threadIdx.x;
    int wave = tid >> 6;
    int lane = tid & 63;
    int l15  = lane & 15;
    int lg   = lane >> 4;                 // 0..3
    int rowbase = blockIdx.x * 128 + wave * 32;

    float4v acc[2][8];
#pragma unroll
    for (int m = 0; m < 2; m++)
#pragma unroll
        for (int nn = 0; nn < 8; nn++)
            acc[m][nn] = (float4v){0.f, 0.f, 0.f, 0.f};

#pragma unroll
    for (int kk = 0; kk < 4; kk++) {
        int k0 = kk * 32 + lg * 8;
        short8v a[2];
#pragma unroll
        for (int m = 0; m < 2; m++) {
            int row = rowbase + m * 16 + l15;
            if (row < n) a[m] = *(const short8v*)&A[row * HID + k0];
            else         a[m] = (short8v){0,0,0,0,0,0,0,0};
        }
        short8v b[8];
#pragma unroll
        for (int nn = 0; nn < 8; nn++)
            b[nn] = *(const short8v*)&Wt[(nn * 16 + l15) * HID + k0];
#pragma unroll
        for (int m = 0; m < 2; m++)
#pragma unroll
            for (int nn = 0; nn < 8; nn++)
                acc[m][nn] = __builtin_amdgcn_mfma_f32_16x16x32_bf16(
                    b[nn], a[m], acc[m][nn], 0, 0, 0);
    }

#pragma unroll
    for (int m = 0; m < 2; m++) {
        int row = rowbase + m * 16 + l15;
        if (row < n) {
            float d = dis[row];
#pragma unroll
            for (int nn = 0; nn < 8; nn++) {
                ushort4 o;
                o.x = f2bf(acc[m][nn][0] * d);
                o.y = f2bf(acc[m][nn][1] * d);
                o.z = f2bf(acc[m][nn][2] * d);
                o.w = f2bf(acc[m][nn][3] * d);
                *(ushort4*)&Y[row * HID + nn * 16 + lg * 4] = o;
            }
        }
    }
}

// ---------------------------------------------------------------------------
// Aggregation (bf16 in/out, f32 accum) — unchanged from round 7
// ---------------------------------------------------------------------------

__global__ __launch_bounds__(256) void aggregate_bf16_kernel(
    const ushort* __restrict__ Y, const int* __restrict__ offs,
    const int* __restrict__ srcs, const float* __restrict__ dis,
    const float* __restrict__ bias, ushort* __restrict__ H, int n)
{
    int tid = threadIdx.x;
    int node = blockIdx.x * 8 + (tid >> 5);
    if (node >= n) return;
    int lane = tid & 31;
    int c = lane * 4;
    const ushort* Yc = Y + c;

    float4 a0 = bf4tof(*(const ushort4*)&Yc[node * HID]);   // self loop
    float4 a1 = make_float4(0.f, 0.f, 0.f, 0.f);
    float4 a2 = make_float4(0.f, 0.f, 0.f, 0.f);
    float4 a3 = make_float4(0.f, 0.f, 0.f, 0.f);
    float4 a4 = make_float4(0.f, 0.f, 0.f, 0.f);
    float4 a5 = make_float4(0.f, 0.f, 0.f, 0.f);
    float4 a6 = make_float4(0.f, 0.f, 0.f, 0.f);
    float4 a7 = make_float4(0.f, 0.f, 0.f, 0.f);

    int beg = offs[node];
    int end = offs[node + 1];
    int j = beg;
    for (; j + 8 <= end; j += 8) {
        int r0 = srcs[j + 0], r1 = srcs[j + 1], r2 = srcs[j + 2], r3 = srcs[j + 3];
        int r4 = srcs[j + 4], r5 = srcs[j + 5], r6 = srcs[j + 6], r7 = srcs[j + 7];
        float4 v0 = bf4tof(*(const ushort4*)&Yc[r0 * HID]);
        float4 v1 = bf4tof(*(const ushort4*)&Yc[r1 * HID]);
        float4 v2 = bf4tof(*(const ushort4*)&Yc[r2 * HID]);
        float4 v3 = bf4tof(*(const ushort4*)&Yc[r3 * HID]);
        float4 v4 = bf4tof(*(const ushort4*)&Yc[r4 * HID]);
        float4 v5 = bf4tof(*(const ushort4*)&Yc[r5 * HID]);
        float4 v6 = bf4tof(*(const ushort4*)&Yc[r6 * HID]);
        float4 v7 = bf4tof(*(const ushort4*)&Yc[r7 * HID]);
        a0.x += v0.x; a0.y += v0.y; a0.z += v0.z; a0.w += v0.w;
        a1.x += v1.x; a1.y += v1.y; a1.z += v1.z; a1.w += v1.w;
        a2.x += v2.x; a2.y += v2.y; a2.z += v2.z; a2.w += v2.w;
        a3.x += v3.x; a3.y += v3.y; a3.z += v3.z; a3.w += v3.w;
        a4.x += v4.x; a4.y += v4.y; a4.z += v4.z; a4.w += v4.w;
        a5.x += v5.x; a5.y += v5.y; a5.z += v5.z; a5.w += v5.w;
        a6.x += v6.x; a6.y += v6.y; a6.z += v6.z; a6.w += v6.w;
        a7.x += v7.x; a7.y += v7.y; a7.z += v7.z; a7.w += v7.w;
    }
    for (; j + 2 <= end; j += 2) {
        int r0 = srcs[j + 0], r1 = srcs[j + 1];
        float4 v0 = bf4tof(*(const ushort4*)&Yc[r0 * HID]);
        float4 v1 = bf4tof(*(const ushort4*)&Yc[r1 * HID]);
        a0.x += v0.x; a0.y += v0.y; a0.z += v0.z; a0.w += v0.w;
        a1.x += v1.x; a1.y += v1.y; a1.z += v1.z; a1.w += v1.w;
    }
    if (j < end) {
        int r0 = srcs[j];
        float4 v0 = bf4tof(*(const ushort4*)&Yc[r0 * HID]);
        a0.x += v0.x; a0.y += v0.y; a0.z += v0.z; a0.w += v0.w;
    }

    a0.x += a1.x + a2.x + a3.x + a4.x + a5.x + a6.x + a7.x;
    a0.y += a1.y + a2.y + a3.y + a4.y + a5.y + a6.y + a7.y;
    a0.z += a1.z + a2.z + a3.z + a4.z + a5.z + a6.z + a7.z;
    a0.w += a1.w + a2.w + a3.w + a4.w + a5.w + a6.w + a7.w;

    float d = dis[node];
    float4 bb = *(const float4*)&bias[c];
    ushort4 o;
    o.x = f2bf(fmaxf(fmaf(d, a0.x, bb.x), 0.f));
    o.y = f2bf(fmaxf(fmaf(d, a0.y, bb.y), 0.f));
    o.z = f2bf(fmaxf(fmaf(d, a0.z, bb.z), 0.f));
    o.w = f2bf(fmaxf(fmaf(d, a0.w, bb.w), 0.f));
    *(ushort4*)&H[node * HID + c] = o;
}

// ---------------------------------------------------------------------------
// Mean-pool (bf16 input) — unchanged
// ---------------------------------------------------------------------------

__global__ __launch_bounds__(256) void pool_kernel(
    const ushort* __restrict__ H, const int* __restrict__ batch,
    float* __restrict__ gsum, float* __restrict__ gcnt, int n)
{
    int half = blockIdx.x * 8 + (threadIdx.x >> 5);
    int lane = threadIdx.x & 31;
    int c = lane * 4;
    int n0 = half * 16;
    if (n0 >= n) return;
    int n1 = min(n0 + 16, n);

    float4 acc = make_float4(0.f, 0.f, 0.f, 0.f);
    float cntv = 0.f;
    int gprev = batch[n0];
    for (int v = n0; v < n1; v++) {
        int g = batch[v];
        if (g != gprev) {
            atomicAdd(&gsum[gprev * HID + c + 0], acc.x);
            atomicAdd(&gsum[gprev * HID + c + 1], acc.y);
            atomicAdd(&gsum[gprev * HID + c + 2], acc.z);
            atomicAdd(&gsum[gprev * HID + c + 3], acc.w);
            if (lane == 0) atomicAdd(&gcnt[gprev], cntv);
            acc = make_float4(0.f, 0.f, 0.f, 0.f);
            cntv = 0.f;
            gprev = g;
        }
        float4 h = bf4tof(*(const ushort4*)&H[v * HID + c]);
        acc.x += h.x; acc.y += h.y; acc.z += h.z; acc.w += h.w;
        cntv += 1.f;
    }
    atomicAdd(&gsum[gprev * HID + c + 0], acc.x);
    atomicAdd(&gsum[gprev * HID + c + 1], acc.y);
    atomicAdd(&gsum[gprev * HID + c + 2], acc.z);
    atomicAdd(&gsum[gprev * HID + c + 3], acc.w);
    if (lane == 0) atomicAdd(&gcnt[gprev], cntv);
}

// ---------------------------------------------------------------------------
// Classifier — unchanged
// ---------------------------------------------------------------------------

__global__ __launch_bounds__(128) void classify_kernel(
    const float* __restrict__ gsum, const float* __restrict__ gcnt,
    const float* __restrict__ lin_w, const float* __restrict__ lin_b,
    float* __restrict__ out)
{
    __shared__ float sp[HID];
    int g = blockIdx.x;
    int f = threadIdx.x;
    float denom = fmaxf(gcnt[g], 1.0f);
    sp[f] = gsum[g * HID + f] / denom;
    __syncthreads();
    if (f < NCLS) {
        float acc = lin_b[f];
        for (int k = 0; k < HID; k++) acc = fmaf(sp[k], lin_w[k * NCLS + f], acc);
        out[g * NCLS + f] = acc;
    }
}

// ---------------------------------------------------------------------------
// Launch
// ---------------------------------------------------------------------------

extern "C" void kernel_launch(void* const* d_in, const int* in_sizes, int n_in,
                              void* d_out, int out_size, void* d_ws, size_t ws_size,
                              hipStream_t stream) {
    const float* x     = (const float*)d_in[0];
    const int*   ei    = (const int*)d_in[1];
    const int*   batch = (const int*)d_in[2];
    const float* W0    = (const float*)d_in[3];
    const float* b0    = (const float*)d_in[4];
    const float* W1    = (const float*)d_in[5];
    const float* b1    = (const float*)d_in[6];
    const float* W2    = (const float*)d_in[7];
    const float* b2    = (const float*)d_in[8];
    const float* lin_w = (const float*)d_in[9];
    const float* lin_b = (const float*)d_in[10];
    float* out = (float*)d_out;

    const int n = in_sizes[0] / HID;      // 50000
    const int E = in_sizes[1] / 2;        // 800000
    const int nb = (n + 255) / 256;       // 196 dest buckets
    const int nsec = (E + EPB - 1) / EPB; // 196 edge sections

    // Workspace carve-up (all offsets 256B-aligned)
    char* w = (char*)d_ws;
    auto carve = [&](size_t bytes) {
        void* p = (void*)w;
        w += (bytes + 255) & ~(size_t)255;
        return p;
    };
    int2*   part   = (int2*)carve((size_t)E * 8);
    int*    lscan  = (int*)carve((size_t)nsec * (nb + 1) * 4);
    int*    btot   = (int*)carve((size_t)nb * 4);
    int*    gstart = (int*)carve((size_t)(nb + 1) * 4);
    int*    offs   = (int*)carve(((size_t)n + 1) * 4);
    int*    srcs   = (int*)carve((size_t)E * 4);
    float*  dis    = (float*)carve((size_t)n * 4);
    ushort* xb     = (ushort*)carve((size_t)n * HID * 2);
    ushort* Wt0    = (ushort*)carve((size_t)HID * HID * 2);
    ushort* Wt1    = (ushort*)carve((size_t)HID * HID * 2);
    ushort* Wt2    = (ushort*)carve((size_t)HID * HID * 2);
    ushort* Y      = (ushort*)carve((size_t)n * HID * 2);
    ushort* Hb     = (ushort*)carve((size_t)n * HID * 2);
    float*  gsum   = (float*)carve((size_t)NGRAPH * HID * 4);
    float*  gcnt   = (float*)carve((size_t)NGRAPH * 4);

    hipMemsetAsync(btot, 0, (size_t)nb * 4, stream);
    hipMemsetAsync(gsum, 0, (size_t)NGRAPH * HID * 4, stream);
    hipMemsetAsync(gcnt, 0, (size_t)NGRAPH * 4, stream);

    const int TB = 256;

    // CSR build (bucketed counting sort, block-local writes)
    part_kernel<<<nsec, TB, 0, stream>>>(ei, part, lscan, btot, E, nb);
    gscan_kernel<<<1, TB, 0, stream>>>(btot, gstart, nb, E);
    csr_kernel<<<nb, TB, 0, stream>>>(part, lscan, gstart, offs, srcs, dis, n, E, nb, nsec);

    // dtype conversions
    int totalx = n * HID;
    cvtx_kernel<<<(totalx / 4 + TB - 1) / TB, TB, 0, stream>>>(x, xb, totalx);
    cvtw_kernel<<<64, 256, 0, stream>>>(W0, Wt0);
    cvtw_kernel<<<64, 256, 0, stream>>>(W1, Wt1);
    cvtw_kernel<<<64, 256, 0, stream>>>(W2, Wt2);

    int gGemm = (n + 127) / 128;          // 391
    int gAgg  = (n + 7) / 8;              // 6250

    // Layer 1
    gemm_bf16_kernel<<<gGemm, TB, 0, stream>>>(xb, Wt0, dis, Y, n);
    aggregate_bf16_kernel<<<gAgg, TB, 0, stream>>>(Y, offs, srcs, dis, b0, Hb, n);
    // Layer 2
    gemm_bf16_kernel<<<gGemm, TB, 0, stream>>>(Hb, Wt1, dis, Y, n);
    aggregate_bf16_kernel<<<gAgg, TB, 0, stream>>>(Y, offs, srcs, dis, b1, Hb, n);
    // Layer 3
    gemm_bf16_kernel<<<gGemm, TB, 0, stream>>>(Hb, Wt2, dis, Y, n);
    aggregate_bf16_kernel<<<gAgg, TB, 0, stream>>>(Y, offs, srcs, dis, b2, Hb, n);

    // Pool + classify
    int halves = (n + 15) / 16;
    int gPool = (halves + 7) / 8;
    pool_kernel<<<gPool, TB, 0, stream>>>(Hb, batch, gsum, gcnt, n);
    classify_kernel<<<NGRAPH, 128, 0, stream>>>(gsum, gcnt, lin_w, lin_b, out);
}